// Round 9
// baseline (729.093 us; speedup 1.0000x reference)
//
#include <hip/hip_runtime.h>

#define BB 256
#define TT 2048
#define II 128
#define HH 128
#define GS 16              // steps per group
#define NG (TT / GS)       // 128 groups

typedef __attribute__((ext_vector_type(8))) short short8;  // 8 bf16 (4 VGPR)
typedef __attribute__((ext_vector_type(4))) float f32x4;   // MFMA C/D

// Group barrier: drain own LDS ops then barrier (vmcnt NOT drained —
// out-stores / x-prefetch loads fly across groups).
__device__ __forceinline__ void group_barrier() {
    asm volatile("s_waitcnt lgkmcnt(0)\n\ts_barrier" ::: "memory");
}

__device__ __forceinline__ float tanh_fast(float s) {
    // tanh(s) = 1 - 2/(e^{2s}+1); e^{2s} = 2^(s * 2/ln2), one v_exp_f32.
#if __has_builtin(__builtin_amdgcn_exp2f)
    const float e = __builtin_amdgcn_exp2f(s * 2.8853900817779268f);
#else
    const float e = exp2f(s * 2.8853900817779268f);
#endif
    return 1.0f - 2.0f * __builtin_amdgcn_rcpf(e + 1.0f);
}

// float -> bf16 round-to-nearest-even (setup paths)
__device__ __forceinline__ unsigned int f2bf(float f) {
    unsigned int u = __float_as_uint(f);
    u += 0x7FFF + ((u >> 16) & 1);
    return u >> 16;
}
// hot-path pack: ONE v_cvt_pk_bf16_f32 (lo = a, hi = b)
__device__ __forceinline__ unsigned int cvtpk(float a, float b) {
    unsigned int r;
    asm("v_cvt_pk_bf16_f32 %0, %1, %2" : "=v"(r) : "v"(a), "v"(b));
    return r;
}

// R22: SINGLE-WAVE recurrence — kill the per-step barrier. The 4h-wave
// structure paid ~90c barrier+wake and a cross-wave LDS exchange every
// step (545 c/step measured). Now wave 0 computes ALL 128 cols per step:
// broadcast-A x 32 MFMAs (8 independent 4-deep chains, interleaved at
// pipe rate); lane l owns cols l and l+64 (col = nt*16+(l&15); nt=l>>4,
// l>>4+4). Per-step h exchange is SAME-WAVE LDS write->read (DS pipe is
// in-order per wave): no s_barrier in the steady step. Seeds: d0..3[0]=
// ax[col l], d4..7[0]=ax[col l+64] — per-lane C gives every lane the
// right bias for the 2 accumulators it consumes; d*[1..3] accumulate
// unread bounded garbage (R16 trick). Out: lane l stores fp32 tanh for
// cols l,l+64 directly (coalesced, fire-and-forget) — no x-wave pacing.
// x-waves (4) only produce axbuf (distance-2, 3 buffers) + staging, one
// window per group, ONE barrier per 16 steps. hA/W_hh use the original
// un-permuted R13 layout (A-frag k = kf*32+(l>>4)*8+e, proven).
__launch_bounds__(320, 1)
__global__ void rnn_pipe(const float* __restrict__ x,
                         const float* __restrict__ w_ih,
                         const float* __restrict__ w_hh,
                         const float* __restrict__ b_ih,
                         const float* __restrict__ b_hh,
                         float* __restrict__ out) {
    const int b    = blockIdx.x;
    const int tid  = threadIdx.x;
    const int wave = tid >> 6;
    const int lane = tid & 63;
    const bool hw  = (wave == 0);

    __shared__ __align__(16) unsigned short hA[2][HH];           // bf16 h ping-pong (linear k)
    __shared__ __align__(16) float axbuf[3][GS][HH];             // 24 KB, distance-2 pipeline
    __shared__ __align__(16) unsigned short xstage[2][4][64][8]; // 8 KB bf16 A-frags

    const float* xb = x + (size_t)b * (TT * II);
    const f32x4 z4 = {0.f, 0.f, 0.f, 0.f};
    const int c16 = lane & 15;
    const int rg  = lane >> 4;       // row-group 0..3

    // ---------------- h-wave setup: W_hh B-frags for ALL 8 n-tiles ----------------
    short8 WH[8][4];                 // 128 VGPR — fine at 1 block/CU
    if (hw) {
#pragma unroll
        for (int nt = 0; nt < 8; ++nt) {
            const int jj = nt * 16 + c16;
#pragma unroll
            for (int kf = 0; kf < 4; ++kf) {
                const float* wp = w_hh + (size_t)jj * HH + kf * 32 + rg * 8;
                short8 s;
#pragma unroll
                for (int e = 0; e < 8; ++e) s[e] = (short)f2bf(wp[e]);
                WH[nt][kf] = s;
            }
        }
    }

    // ---------------- x-wave setup (waves 1..4) ----------------
    const int xwq = wave - 1;        // 0..3
    const int jb  = xwq * 32;        // owns j in [jb, jb+32): 2 N-tiles
    short8 WF[2][4];
    float biasv[2];
    const int q   = tid - 64;        // 0..255 for x-threads
    const int t_s = q >> 4;          // 0..15
    const int m   = q & 15;
    const int i0  = m * 8;
    const int kfs = m >> 2;                  // k-frag of this chunk
    const int lps = (m & 3) * 16 + t_s;      // A-frag lane slot
    if (!hw) {
#pragma unroll
        for (int nt = 0; nt < 2; ++nt) {
            const int jj = jb + nt * 16 + c16;
            biasv[nt] = b_ih[jj] + b_hh[jj];
#pragma unroll
            for (int kf = 0; kf < 4; ++kf) {
                const float* wp = w_ih + (size_t)jj * II + kf * 32 + rg * 8;
                short8 s;
#pragma unroll
                for (int e = 0; e < 8; ++e) s[e] = (short)f2bf(wp[e]);
                WF[nt][kf] = s;
            }
        }
    }

#define STAGE_X(BUF, R0, R1) do { \
        uint4 P_; \
        P_.x = cvtpk((R0).x, (R0).y); P_.y = cvtpk((R0).z, (R0).w); \
        P_.z = cvtpk((R1).x, (R1).y); P_.w = cvtpk((R1).z, (R1).w); \
        *reinterpret_cast<uint4*>(&xstage[BUF][kfs][lps][0]) = P_; } while (0)

// chained XPROJ — runs on x-waves, off the serial path (full group of slack)
#define XPROJ(SB, AB) do { \
        const short8 PA0 = *reinterpret_cast<const short8*>(&xstage[SB][0][lane][0]); \
        const short8 PA1 = *reinterpret_cast<const short8*>(&xstage[SB][1][lane][0]); \
        const short8 PA2 = *reinterpret_cast<const short8*>(&xstage[SB][2][lane][0]); \
        const short8 PA3 = *reinterpret_cast<const short8*>(&xstage[SB][3][lane][0]); \
        f32x4 ac0 = z4, ac1 = z4; \
        ac0 = __builtin_amdgcn_mfma_f32_16x16x32_bf16(PA0, WF[0][0], ac0, 0, 0, 0); \
        ac0 = __builtin_amdgcn_mfma_f32_16x16x32_bf16(PA1, WF[0][1], ac0, 0, 0, 0); \
        ac0 = __builtin_amdgcn_mfma_f32_16x16x32_bf16(PA2, WF[0][2], ac0, 0, 0, 0); \
        ac0 = __builtin_amdgcn_mfma_f32_16x16x32_bf16(PA3, WF[0][3], ac0, 0, 0, 0); \
        ac1 = __builtin_amdgcn_mfma_f32_16x16x32_bf16(PA0, WF[1][0], ac1, 0, 0, 0); \
        ac1 = __builtin_amdgcn_mfma_f32_16x16x32_bf16(PA1, WF[1][1], ac1, 0, 0, 0); \
        ac1 = __builtin_amdgcn_mfma_f32_16x16x32_bf16(PA2, WF[1][2], ac1, 0, 0, 0); \
        ac1 = __builtin_amdgcn_mfma_f32_16x16x32_bf16(PA3, WF[1][3], ac1, 0, 0, 0); \
        const int rb_ = rg * 4; \
        _Pragma("unroll") \
        for (int r = 0; r < 4; ++r) { \
            axbuf[AB][rb_ + r][jb + c16]      = ac0[r] + biasv[0]; \
            axbuf[AB][rb_ + r][jb + 16 + c16] = ac1[r] + biasv[1]; \
        } } while (0)

    // -------- prologue: prime axbuf[0],[1]; xstage[0]<-x(g2); nr<-x(g3) --------
    float4 nr0, nr1;
    if (!hw) {
        float4 p0 = *reinterpret_cast<const float4*>(&xb[t_s * II + i0]);
        float4 p1 = *reinterpret_cast<const float4*>(&xb[t_s * II + i0 + 4]);
        STAGE_X(0, p0, p1);                    // x of group 0
    }
    if (tid < 2 * HH) ((unsigned short*)hA)[tid] = 0;  // zero both parities
    __syncthreads();
    if (!hw) XPROJ(0, 0);                      // axbuf[0] <- ax(group 0)
    __syncthreads();
    if (!hw) {
        float4 p0 = *reinterpret_cast<const float4*>(&xb[(GS + t_s) * II + i0]);
        float4 p1 = *reinterpret_cast<const float4*>(&xb[(GS + t_s) * II + i0 + 4]);
        STAGE_X(0, p0, p1);                    // x of group 1 (reuse buf 0)
    }
    __syncthreads();
    if (!hw) XPROJ(0, 1);                      // axbuf[1] <- ax(group 1)
    __syncthreads();
    if (!hw) {
        float4 p0 = *reinterpret_cast<const float4*>(&xb[(2 * GS + t_s) * II + i0]);
        float4 p1 = *reinterpret_cast<const float4*>(&xb[(2 * GS + t_s) * II + i0 + 4]);
        STAGE_X(0, p0, p1);                    // xstage[0] <- x(g2) (window g=0 reads it)
        nr0 = *reinterpret_cast<const float4*>(&xb[(size_t)(3 * GS + t_s) * II + i0]);
        nr1 = *reinterpret_cast<const float4*>(&xb[(size_t)(3 * GS + t_s) * II + i0 + 4]);
    }
    __syncthreads();

    if (hw) {
        // ================= h-wave: the serial recurrence, barrier-free steps =================
        __builtin_amdgcn_s_setprio(1);
        float* op = out + (size_t)b * (TT * HH) + lane;   // cols l, l+64 per step
        // persistent accumulators; [1..3] hold unread bounded garbage
        f32x4 d0 = z4, d1 = z4, d2 = z4, d3 = z4, d4 = z4, d5 = z4, d6 = z4, d7 = z4;

        for (int g = 0; g < NG; ++g) {
            const float* axg = &axbuf[g % 3][0][0];
#pragma unroll 4
            for (int w = 0; w < GS; ++w) {
                const int p  = w & 1;
                const int ko = rg * 8;
                // broadcast-A reads (16-lane groups read same address: free)
                const short8 A0 = *reinterpret_cast<const short8*>(&hA[p][ 0 + ko]);
                const short8 A1 = *reinterpret_cast<const short8*>(&hA[p][32 + ko]);
                const short8 A2 = *reinterpret_cast<const short8*>(&hA[p][64 + ko]);
                const short8 A3 = *reinterpret_cast<const short8*>(&hA[p][96 + ko]);
                const float ax0 = axg[w * HH + lane];        // ax[col l]
                const float ax1 = axg[w * HH + lane + 64];   // ax[col l+64]
                // per-lane C seeds: lane l consumes d[rg][0] and d[rg+4][0]
                d0[0] = ax0; d1[0] = ax0; d2[0] = ax0; d3[0] = ax0;
                d4[0] = ax1; d5[0] = ax1; d6[0] = ax1; d7[0] = ax1;
                // 32 MFMAs: 8 independent 4-deep chains, kf-major interleave
#define HR(Ak, kf) \
                d0 = __builtin_amdgcn_mfma_f32_16x16x32_bf16(Ak, WH[0][kf], d0, 0, 0, 0); \
                d1 = __builtin_amdgcn_mfma_f32_16x16x32_bf16(Ak, WH[1][kf], d1, 0, 0, 0); \
                d2 = __builtin_amdgcn_mfma_f32_16x16x32_bf16(Ak, WH[2][kf], d2, 0, 0, 0); \
                d3 = __builtin_amdgcn_mfma_f32_16x16x32_bf16(Ak, WH[3][kf], d3, 0, 0, 0); \
                d4 = __builtin_amdgcn_mfma_f32_16x16x32_bf16(Ak, WH[4][kf], d4, 0, 0, 0); \
                d5 = __builtin_amdgcn_mfma_f32_16x16x32_bf16(Ak, WH[5][kf], d5, 0, 0, 0); \
                d6 = __builtin_amdgcn_mfma_f32_16x16x32_bf16(Ak, WH[6][kf], d6, 0, 0, 0); \
                d7 = __builtin_amdgcn_mfma_f32_16x16x32_bf16(Ak, WH[7][kf], d7, 0, 0, 0);
                HR(A0, 0) HR(A1, 1) HR(A2, 2) HR(A3, 3)
#undef HR
                // select this lane's two columns (static regs + cndmask)
                float s0 = d0[0];
                s0 = (rg == 1) ? d1[0] : s0;
                s0 = (rg == 2) ? d2[0] : s0;
                s0 = (rg == 3) ? d3[0] : s0;
                float s1 = d4[0];
                s1 = (rg == 1) ? d5[0] : s1;
                s1 = (rg == 2) ? d6[0] : s1;
                s1 = (rg == 3) ? d7[0] : s1;
                const float hn0 = tanh_fast(s0);
                const float hn1 = tanh_fast(s1);
                const unsigned int pk = cvtpk(hn0, hn1);
                // same-wave LDS h update (in-order DS pipe: next step's reads
                // see these writes without any barrier)
                hA[p ^ 1][lane]      = (unsigned short)pk;
                hA[p ^ 1][lane + 64] = (unsigned short)(pk >> 16);
                // fp32 out, coalesced, fire-and-forget
                op[0]  = hn0;
                op[64] = hn1;
                op += HH;
            }
            group_barrier();   // once per 16 steps: ax handoff with x-waves
        }
    } else {
        // ================= x-waves: one window per group, then park at barrier =================
        for (int g = 0; g < NG; ++g) {
            if (g + 2 < NG) {
                XPROJ(g & 1, (g + 2) % 3);       // axbuf[(g+2)%3] <- ax(g+2) from xstage[g&1]
            }
            if (g + 3 < NG) {
                STAGE_X((g + 1) & 1, nr0, nr1);  // xstage[(g+1)&1] <- x(g+3)
            }
            if (g + 4 < NG) {
                const int tb = (g + 4) * GS;     // load x(g+4) for next window
                nr0 = *reinterpret_cast<const float4*>(&xb[(size_t)(tb + t_s) * II + i0]);
                nr1 = *reinterpret_cast<const float4*>(&xb[(size_t)(tb + t_s) * II + i0 + 4]);
            }
            group_barrier();
        }
    }
#undef XPROJ
#undef STAGE_X
}

extern "C" void kernel_launch(void* const* d_in, const int* in_sizes, int n_in,
                              void* d_out, int out_size, void* d_ws, size_t ws_size,
                              hipStream_t stream) {
    const float* x    = (const float*)d_in[0];
    const float* w_ih = (const float*)d_in[1];
    const float* w_hh = (const float*)d_in[2];
    const float* b_ih = (const float*)d_in[3];
    const float* b_hh = (const float*)d_in[4];
    float* out = (float*)d_out;

    rnn_pipe<<<BB, 320, 0, stream>>>(x, w_ih, w_hh, b_ih, b_hh, out);
}

// Round 10
// 464.415 us; speedup vs baseline: 1.5699x; 1.5699x over previous
//
#include <hip/hip_runtime.h>

#define BB 256
#define TT 2048
#define II 128
#define HH 128
#define GS 16              // steps per group
#define NG (TT / GS)       // 128 groups

typedef __attribute__((ext_vector_type(8))) short short8;  // 8 bf16 (4 VGPR)
typedef __attribute__((ext_vector_type(4))) float f32x4;   // MFMA C/D

// Light per-step barrier: drain LDS ops then barrier in ONE asm block
// (vmcnt NOT drained — x-prefetch loads / out-stores fly across steps).
__device__ __forceinline__ void step_barrier() {
    asm volatile("s_waitcnt lgkmcnt(0)\n\ts_barrier" ::: "memory");
}

__device__ __forceinline__ float tanh_fast(float s) {
    // tanh(s) = 1 - 2/(e^{2s}+1); e^{2s} = 2^(s * 2/ln2), one v_exp_f32.
#if __has_builtin(__builtin_amdgcn_exp2f)
    const float e = __builtin_amdgcn_exp2f(s * 2.8853900817779268f);
#else
    const float e = exp2f(s * 2.8853900817779268f);
#endif
    return 1.0f - 2.0f * __builtin_amdgcn_rcpf(e + 1.0f);
}

// float -> bf16 round-to-nearest-even (scalar/setup paths)
__device__ __forceinline__ unsigned int f2bf(float f) {
    unsigned int u = __float_as_uint(f);
    u += 0x7FFF + ((u >> 16) & 1);
    return u >> 16;
}
// hot-path pack: ONE v_cvt_pk_bf16_f32 (lo = a, hi = b)
__device__ __forceinline__ unsigned int cvtpk(float a, float b) {
    unsigned int r;
    asm("v_cvt_pk_bf16_f32 %0, %1, %2" : "=v"(r) : "v"(a), "v"(b));
    return r;
}

// R23 = R18/R21 verbatim — the session's verified optimum (465.7/464.7 µs,
// twice reproduced). Structural search is closed by measurement:
//   R15 (merge x into h):      +95 c/step  — role-split is load-bearing
//   R17 (park x-waves):        −12 c/step  — kept
//   R18 (strip h tail to x):   −80 c/step  — kept
//   R20 (replicated hA):       +77 c/step  — bank conflicts on serial chain
//   R22 (single-wave, no bar): +284 c/step — 32 MFMAs serialize on 1 SIMD
//                                            (16 cyc/MFMA/SIMD; 515c vs 129c)
// Remaining step budget (~545c): MFMA pipe 129 + bcast ds_read ~120 +
// result lat ~40 + tanh/pack ~50 + write+drain ~40 + 8-wave barrier ~60-90
// + slop. All components attacked; survivors irreducible in any structure
// with a defensible cycle count. Serial tanh-RNN: latency floor, not a
// counter roofline.
__launch_bounds__(512, 1)
__global__ void rnn_pipe(const float* __restrict__ x,
                         const float* __restrict__ w_ih,
                         const float* __restrict__ w_hh,
                         const float* __restrict__ b_ih,
                         const float* __restrict__ b_hh,
                         float* __restrict__ out) {
    const int b    = blockIdx.x;
    const int tid  = threadIdx.x;
    const int wave = tid >> 6;
    const int lane = tid & 63;
    const bool hw  = (wave < 4);

    __shared__ __align__(16) unsigned short hA[2][HH];           // bf16 h ping-pong (k-permuted)
    __shared__ __align__(16) float axbuf[3][GS][HH];             // 24 KB, distance-2 pipeline
    __shared__ __align__(16) unsigned short xstage[2][4][64][8]; // 8 KB bf16 A-frags

    const float* xb = x + (size_t)b * (TT * II);
    const f32x4 z4 = {0.f, 0.f, 0.f, 0.f};   // hoisted MFMA C zero

    // ---------------- h-wave setup: W_hh B-frags (bf16, k-permuted) ----------------
    const int jb_h = (wave & 3) * 32;    // h-wave owns cols [jb_h, jb_h+32)
    short8 WH[2][4];
    if (hw) {
#pragma unroll
        for (int nt = 0; nt < 2; ++nt) {
            const int jj = jb_h + nt * 16 + (lane & 15);
#pragma unroll
            for (int kf = 0; kf < 4; ++kf) {
                short8 s;
#pragma unroll
                for (int e = 0; e < 8; ++e) {
                    const int kp = kf * 32 + (lane >> 4) * 8 + e;  // A-slot index
                    const int mm = kp & 31;
                    // slot -> original k: 32a+2c -> 32a+c ; 32a+2c+1 -> 32a+16+c
                    const int ko = (kp & ~31) + (mm >> 1) + ((mm & 1) << 4);
                    s[e] = (short)f2bf(w_hh[(size_t)jj * HH + ko]);
                }
                WH[nt][kf] = s;
            }
        }
    }

    // ---------------- x-wave setup ----------------
    const int xwq = wave - 4;        // 0..3
    const int jb  = xwq * 32;        // owns j in [jb, jb+32): 2 N-tiles
    short8 WF[2][4];
    float biasv[2];
    f32x4 bs0 = z4, bs1 = z4;        // bias splats (MFMA C seeds)
    const int q   = tid - 256;       // 0..255 for x-threads
    const int t_s = q >> 4;          // 0..15
    const int m   = q & 15;
    const int i0  = m * 8;
    const int kfs = m >> 2;                  // k-frag of this chunk
    const int lps = (m & 3) * 16 + t_s;      // A-frag lane slot
    const int c16 = lane & 15;
    if (!hw) {
#pragma unroll
        for (int nt = 0; nt < 2; ++nt) {
            const int jj = jb + nt * 16 + (lane & 15);
            biasv[nt] = b_ih[jj] + b_hh[jj];
#pragma unroll
            for (int kf = 0; kf < 4; ++kf) {
                const float* wp = w_ih + (size_t)jj * II + kf * 32 + (lane >> 4) * 8;
                short8 s;
#pragma unroll
                for (int e = 0; e < 8; ++e) s[e] = (short)f2bf(wp[e]);
                WF[nt][kf] = s;
            }
        }
#pragma unroll
        for (int r = 0; r < 4; ++r) { bs0[r] = biasv[0]; bs1[r] = biasv[1]; }
    }

#define STAGE_X(BUF, R0, R1) do { \
        uint4 P_; \
        P_.x = cvtpk((R0).x, (R0).y); P_.y = cvtpk((R0).z, (R0).w); \
        P_.z = cvtpk((R1).x, (R1).y); P_.w = cvtpk((R1).z, (R1).w); \
        *reinterpret_cast<uint4*>(&xstage[BUF][kfs][lps][0]) = P_; } while (0)

// chained XPROJ — used in the prologue only (not perf-critical)
#define XPROJ(SB, AB) do { \
        const short8 PA0 = *reinterpret_cast<const short8*>(&xstage[SB][0][lane][0]); \
        const short8 PA1 = *reinterpret_cast<const short8*>(&xstage[SB][1][lane][0]); \
        const short8 PA2 = *reinterpret_cast<const short8*>(&xstage[SB][2][lane][0]); \
        const short8 PA3 = *reinterpret_cast<const short8*>(&xstage[SB][3][lane][0]); \
        f32x4 ac0 = z4, ac1 = z4; \
        ac0 = __builtin_amdgcn_mfma_f32_16x16x32_bf16(PA0, WF[0][0], ac0, 0, 0, 0); \
        ac0 = __builtin_amdgcn_mfma_f32_16x16x32_bf16(PA1, WF[0][1], ac0, 0, 0, 0); \
        ac0 = __builtin_amdgcn_mfma_f32_16x16x32_bf16(PA2, WF[0][2], ac0, 0, 0, 0); \
        ac0 = __builtin_amdgcn_mfma_f32_16x16x32_bf16(PA3, WF[0][3], ac0, 0, 0, 0); \
        ac1 = __builtin_amdgcn_mfma_f32_16x16x32_bf16(PA0, WF[1][0], ac1, 0, 0, 0); \
        ac1 = __builtin_amdgcn_mfma_f32_16x16x32_bf16(PA1, WF[1][1], ac1, 0, 0, 0); \
        ac1 = __builtin_amdgcn_mfma_f32_16x16x32_bf16(PA2, WF[1][2], ac1, 0, 0, 0); \
        ac1 = __builtin_amdgcn_mfma_f32_16x16x32_bf16(PA3, WF[1][3], ac1, 0, 0, 0); \
        const int c_ = lane & 15, rb_ = (lane >> 4) * 4; \
        _Pragma("unroll") \
        for (int r = 0; r < 4; ++r) { \
            axbuf[AB][rb_ + r][jb + c_]      = ac0[r] + biasv[0]; \
            axbuf[AB][rb_ + r][jb + 16 + c_] = ac1[r] + biasv[1]; \
        } } while (0)

    // ---------------- prologue: prime axbuf[0],[1]; xstage[0]<-x(g2); nr<-x(g3) ----------------
    float4 nr0, nr1;
    if (!hw) {
        float4 p0 = *reinterpret_cast<const float4*>(&xb[t_s * II + i0]);
        float4 p1 = *reinterpret_cast<const float4*>(&xb[t_s * II + i0 + 4]);
        STAGE_X(0, p0, p1);                    // x of group 0
    }
    if (tid < HH) hA[0][tid] = 0;              // bf16 zero (permutation-invariant)
    __syncthreads();
    if (!hw) XPROJ(0, 0);                      // axbuf[0] <- ax(group 0)
    __syncthreads();
    if (!hw) {
        float4 p0 = *reinterpret_cast<const float4*>(&xb[(GS + t_s) * II + i0]);
        float4 p1 = *reinterpret_cast<const float4*>(&xb[(GS + t_s) * II + i0 + 4]);
        STAGE_X(0, p0, p1);                    // x of group 1 (reuse buf 0)
    }
    __syncthreads();
    if (!hw) XPROJ(0, 1);                      // axbuf[1] <- ax(group 1)
    __syncthreads();
    if (!hw) {
        float4 p0 = *reinterpret_cast<const float4*>(&xb[(2 * GS + t_s) * II + i0]);
        float4 p1 = *reinterpret_cast<const float4*>(&xb[(2 * GS + t_s) * II + i0 + 4]);
        STAGE_X(0, p0, p1);                    // xstage[0] <- x of group 2 (window g=0 reads it)
        nr0 = *reinterpret_cast<const float4*>(&xb[(size_t)(3 * GS + t_s) * II + i0]);
        nr1 = *reinterpret_cast<const float4*>(&xb[(size_t)(3 * GS + t_s) * II + i0 + 4]);
    }
    __syncthreads();

    // h-wave persistent state
    float axn0 = 0.f, axn1 = 0.f;
    f32x4 d00 = z4, d10 = z4;      // persistent ax-seeded accumulators
    if (hw) {
        axn0 = axbuf[0][0][jb_h + c16];
        axn1 = axbuf[0][0][jb_h + 16 + c16];
        __builtin_amdgcn_s_setprio(1);    // protect the serial chain's MFMAs
    }

    // x-wave out-store pointer: lane c<16 -> col jb+c; lane 16+c -> col jb+16+c
    float* xout = nullptr;
    if (!hw && lane < 32) {
        xout = out + (size_t)b * (TT * HH) + jb + c16 + ((lane & 16) ? 16 : 0);
    }

    // ---------------- main loop ----------------
    for (int g = 0; g < NG; ++g) {
        const int g3  = g % 3;             // h read buffer
        const int g3n = (g + 1) % 3;       // h w==15 prefetch buffer
        const int g3x = (g + 2) % 3;       // x window write buffer
#pragma unroll
        for (int w = 0; w < GS; ++w) {
            if (hw) {
                const int p  = w & 1;
                const int ko = (lane >> 4) * 8;
                // A = h broadcast into all 16 rows (permuted k-layout matches WH)
                const short8 A0 = *reinterpret_cast<const short8*>(&hA[p][ 0 + ko]);
                const short8 A1 = *reinterpret_cast<const short8*>(&hA[p][32 + ko]);
                const short8 A2 = *reinterpret_cast<const short8*>(&hA[p][64 + ko]);
                const short8 A3 = *reinterpret_cast<const short8*>(&hA[p][96 + ko]);
                // seed ax into C of the first acc of each n-tile (1 mov each;
                // stale [1..3] never read, bounded accumulation)
                d00[0] = axn0;
                d10[0] = axn1;
                f32x4 e01, e02, e03, e11, e12, e13;
                d00 = __builtin_amdgcn_mfma_f32_16x16x32_bf16(A0, WH[0][0], d00, 0, 0, 0);
                e01 = __builtin_amdgcn_mfma_f32_16x16x32_bf16(A1, WH[0][1], z4,  0, 0, 0);
                e02 = __builtin_amdgcn_mfma_f32_16x16x32_bf16(A2, WH[0][2], z4,  0, 0, 0);
                e03 = __builtin_amdgcn_mfma_f32_16x16x32_bf16(A3, WH[0][3], z4,  0, 0, 0);
                d10 = __builtin_amdgcn_mfma_f32_16x16x32_bf16(A0, WH[1][0], d10, 0, 0, 0);
                e11 = __builtin_amdgcn_mfma_f32_16x16x32_bf16(A1, WH[1][1], z4,  0, 0, 0);
                e12 = __builtin_amdgcn_mfma_f32_16x16x32_bf16(A2, WH[1][2], z4,  0, 0, 0);
                e13 = __builtin_amdgcn_mfma_f32_16x16x32_bf16(A3, WH[1][3], z4,  0, 0, 0);
                // prefetch next step's ax (hidden under MFMA completion).
                // w==15 reads next group's buffer — written a FULL group ago
                // (distance-2 pipeline), so no race with this group's window.
                {
                    const int wn  = (w + 1) & (GS - 1);
                    const int gnb = (w == GS - 1) ? g3n : g3;
                    axn0 = axbuf[gnb][wn][jb_h + c16];
                    axn1 = axbuf[gnb][wn][jb_h + 16 + c16];
                }
                // 2-level add tree (ax already inside d00/d10)
                const float s0 = (d00[0] + e01[0]) + (e02[0] + e03[0]);
                const float s1 = (d10[0] + e11[0]) + (e12[0] + e13[0]);
                const float hn0 = tanh_fast(s0);
                const float hn1 = tanh_fast(s1);
                const unsigned int hpk = cvtpk(hn0, hn1);
                if (lane < 16) {
                    // permuted layout: cols (jb_h+lane, jb_h+16+lane) are
                    // adjacent slots -> ONE packed dword write
                    *reinterpret_cast<unsigned int*>(&hA[p ^ 1][jb_h + 2 * lane]) = hpk;
                }
            } else {
                // ---- park-and-store: stream out[T-1] from hA while h computes T ----
                const int T = (g << 4) + w;
                if (T != 0 && lane < 32) {
                    const unsigned int rd = *reinterpret_cast<const unsigned int*>(
                        &hA[w & 1][jb + 2 * c16]);
                    const unsigned int v = (lane & 16) ? (rd & 0xffff0000u) : (rd << 16);
                    xout[(size_t)(T - 1) * HH] = __uint_as_float(v);
                }
                if (w == 14) {
                    // ---- the ENTIRE per-group x pipeline, one window ----
                    if (g + 2 < NG) {
                        // project ax for group g+2 from xstage[g&1] (staged at window g-1)
                        const short8 XA0 = *reinterpret_cast<const short8*>(&xstage[g & 1][0][lane][0]);
                        const short8 XA1 = *reinterpret_cast<const short8*>(&xstage[g & 1][1][lane][0]);
                        const short8 XA2 = *reinterpret_cast<const short8*>(&xstage[g & 1][2][lane][0]);
                        const short8 XA3 = *reinterpret_cast<const short8*>(&xstage[g & 1][3][lane][0]);
                        // 8 independent MFMAs (bias-seeded first pair) + 2-level tree
                        f32x4 xp0, xp1, xp2, xp3, yp0, yp1, yp2, yp3;
                        xp0 = __builtin_amdgcn_mfma_f32_16x16x32_bf16(XA0, WF[0][0], bs0, 0, 0, 0);
                        yp0 = __builtin_amdgcn_mfma_f32_16x16x32_bf16(XA0, WF[1][0], bs1, 0, 0, 0);
                        xp1 = __builtin_amdgcn_mfma_f32_16x16x32_bf16(XA1, WF[0][1], z4, 0, 0, 0);
                        yp1 = __builtin_amdgcn_mfma_f32_16x16x32_bf16(XA1, WF[1][1], z4, 0, 0, 0);
                        xp2 = __builtin_amdgcn_mfma_f32_16x16x32_bf16(XA2, WF[0][2], z4, 0, 0, 0);
                        yp2 = __builtin_amdgcn_mfma_f32_16x16x32_bf16(XA2, WF[1][2], z4, 0, 0, 0);
                        xp3 = __builtin_amdgcn_mfma_f32_16x16x32_bf16(XA3, WF[0][3], z4, 0, 0, 0);
                        yp3 = __builtin_amdgcn_mfma_f32_16x16x32_bf16(XA3, WF[1][3], z4, 0, 0, 0);
                        const f32x4 t0 = (xp0 + xp1) + (xp2 + xp3);
                        const f32x4 t1 = (yp0 + yp1) + (yp2 + yp3);
                        const int c_ = lane & 15, rb_ = (lane >> 4) * 4;
#pragma unroll
                        for (int r = 0; r < 4; ++r) {
                            axbuf[g3x][rb_ + r][jb + c_]      = t0[r];
                            axbuf[g3x][rb_ + r][jb + 16 + c_] = t1[r];
                        }
                    }
                    if (g + 3 < NG) {
                        STAGE_X((g + 1) & 1, nr0, nr1);   // x of group g+3 (loaded last window)
                    }
                    if (g + 4 < NG) {
                        const int tb = (g + 4) * GS;      // load x of group g+4 for next window
                        nr0 = *reinterpret_cast<const float4*>(&xb[(size_t)(tb + t_s) * II + i0]);
                        nr1 = *reinterpret_cast<const float4*>(&xb[(size_t)(tb + t_s) * II + i0 + 4]);
                    }
                }
            }
            step_barrier();
        }
    }

    // ---------------- epilogue: flush out[TT-1] (in hA[0] after last step) ----------------
    if (!hw && lane < 32) {
        const unsigned int rd = *reinterpret_cast<const unsigned int*>(
            &hA[0][jb + 2 * c16]);
        const unsigned int v = (lane & 16) ? (rd & 0xffff0000u) : (rd << 16);
        xout[(size_t)(TT - 1) * HH] = __uint_as_float(v);
    }
#undef XPROJ
#undef STAGE_X
}

extern "C" void kernel_launch(void* const* d_in, const int* in_sizes, int n_in,
                              void* d_out, int out_size, void* d_ws, size_t ws_size,
                              hipStream_t stream) {
    const float* x    = (const float*)d_in[0];
    const float* w_ih = (const float*)d_in[1];
    const float* w_hh = (const float*)d_in[2];
    const float* b_ih = (const float*)d_in[3];
    const float* b_hh = (const float*)d_in[4];
    float* out = (float*)d_out;

    rnn_pipe<<<BB, 512, 0, stream>>>(x, w_ih, w_hh, b_ih, b_hh, out);
}